// Round 1
// baseline (239.517 us; speedup 1.0000x reference)
//
#include <hip/hip_runtime.h>

// filtfilt (order-2 biquad, odd-ext pad=9) over 1024 rows x 32768 fp32.
// Scale normalization cancels exactly (linear-homogeneous) -> skipped.
// R3: barrier-free per-WAVE tiles. Each wave owns a private LDS slice and a
// 1088-output segment; intra-wave LDS program-order replaces __syncthreads
// (read bursts strictly precede in-place write bursts in program order, and
// the LDS pipe is in-order per wave). Strides 19/17 (odd) = conflict-free.
// Warmup 16 (err 0.577^16 ~ 1.5e-4); staged zeros make row edges exact.
//
// R4 (this round): __launch_bounds__ 8 -> 4 waves/EU. The (256,8) bound
// capped the allocator at 64 VGPRs while the barrier-free structure requires
// v[35] (all forward-window LDS reads issued before any in-place y1 write ->
// 35 simultaneously-live destinations) + w[33] + coeffs + z-state. Suspected
// forced scratch spills (~1.1 GB extra HBM traffic ~ +175 us) as the gap
// between the 240 us measurement and the ~90 us pipe-sum floor. 128-VGPR
// budget removes the spill pressure; 16 waves/CU remains enough TLP.

#define N_COLS 32768
#define PAD 9
#define LTOT  (N_COLS + 2 * PAD)   // 32786
#define OUTEND (N_COLS + PAD)      // 32777: one past last output (xe coords)
#define WF 16
#define WB 16
#define CF 19                      // fwd chunk/lane (odd -> conflict-free)
#define CB 17                      // bwd chunk/lane (odd -> conflict-free)
#define LANES 64
#define P   (CB * LANES)           // 1088 outputs per wave
#define NSEG 31                    // ceil(32768 / 1088)
#define SLOT (WF + CF * LANES)     // 1232 floats = 4928 B per wave
#define WPB 4
#define TPB 256

__launch_bounds__(TPB, 4)
__global__ void filtfilt_kernel(const float* __restrict__ x,
                                const float* __restrict__ bco,
                                const float* __restrict__ aco,
                                float* __restrict__ out,
                                int rows) {
    __shared__ float xs_all[WPB][SLOT];   // 19,712 B
    const int tid = threadIdx.x;
    const int wid = tid >> 6;
    const int lane = tid & 63;
    float* __restrict__ xs = xs_all[wid];

    const int W = blockIdx.x * WPB + wid;  // global wave index
    const int row = W / NSEG;
    const int seg = W - row * NSEG;
    if (row >= rows) return;               // wave-uniform exit, no barriers used

    const float inv_a0 = 1.0f / aco[0];
    const float B0 = bco[0] * inv_a0;
    const float B1 = bco[1] * inv_a0;
    const float B2 = bco[2] * inv_a0;
    const float A1 = aco[1] * inv_a0;
    const float A2 = aco[2] * inv_a0;

    const int G = PAD + seg * P;           // first output position (xe coords)
    const int A = G - WF;                  // slice origin; -7 for seg0
    const float* __restrict__ xrow = x + (size_t)row * N_COLS;

    // ---- stage interior x via float4 (all offsets/counts are %4==0 by design)
    {
        const int g0 = (A - PAD > 0) ? (A - PAD) : 0;
        int g1 = G + CF * LANES; if (g1 > OUTEND) g1 = OUTEND; g1 -= PAD;
        const int off0 = g0 + PAD - A;     // 0 generic; 16 for seg0
        const float4* __restrict__ xg4 = (const float4*)(xrow + g0);
        float4* __restrict__ s4 = (float4*)(xs + off0);
        const int nvec = (g1 - g0) >> 2;
        for (int i = lane; i < nvec; i += LANES) s4[i] = xg4[i];
    }
    // ---- left edge (seg0): offsets [0,16) = t in [-7, 9): zeros then odd-ext
    if (seg == 0) {
        if (lane < WF) {
            const int t = lane - (WF - PAD);   // -7..8
            xs[lane] = (t >= 0) ? (2.0f * xrow[0] - xrow[PAD - t]) : 0.0f;
        }
    }
    // ---- right edge (last seg): odd-ext then zeros (zeros make fwd exact)
    if (seg == NSEG - 1) {
        const float x_last = xrow[N_COLS - 1];
        for (int o = (OUTEND - A) + lane; o < SLOT; o += LANES) {
            const int t = A + o;
            xs[o] = (t < LTOT) ? (2.0f * x_last - xrow[2 * N_COLS + PAD - 2 - t])
                               : 0.0f;
        }
    }

    // ---- forward: burst-read 35-float window, recurrence in regs, write 19 y1
    // intra-wave ordering: these reads (x) precede all y1 writes in program
    // order; cross-lane WAR is safe because the LDS pipe is in-order per wave.
    const int f_off = CF * lane;           // == (sf - WF) - A
    float v[WF + CF];
#pragma unroll
    for (int k = 0; k < WF + CF; ++k) v[k] = xs[f_off + k];
    {
        float z0 = 0.0f, z1 = 0.0f;
#pragma unroll
        for (int k = 0; k < WF + CF; ++k) {
            const float xv = v[k];
            const float y = fmaf(B0, xv, z0);
            z0 = fmaf(-A1, y, fmaf(B1, xv, z1));
            z1 = fmaf(B2, xv, -A2 * y);
            v[k] = y;
        }
    }
#pragma unroll
    for (int k = WF; k < WF + CF; ++k) xs[f_off + k] = v[k];  // y1 over [G, G+1216)

    // ---- re-zero y1 slack past LTOT (last seg) so bwd zero-state is exact
    if (seg == NSEG - 1) {
        for (int o = (LTOT - A) + lane; o < SLOT; o += LANES) xs[o] = 0.0f;
    }

    // ---- backward: burst-read 33 y1 (pre-overwrite values, by program order),
    // reverse recurrence, write 17 final outputs in place
    const int b_off = CB * lane + WF;      // == sb - A
    float w[CB + WB];
#pragma unroll
    for (int k = 0; k < CB + WB; ++k) w[k] = xs[b_off + k];
    {
        float z0 = 0.0f, z1 = 0.0f;
#pragma unroll
        for (int k = CB + WB - 1; k >= 0; --k) {
            const float xv = w[k];
            const float y = fmaf(B0, xv, z0);
            z0 = fmaf(-A1, y, fmaf(B1, xv, z1));
            z1 = fmaf(B2, xv, -A2 * y);
            if (k < CB) w[k] = y;
        }
    }
#pragma unroll
    for (int k = 0; k < CB; ++k) xs[b_off + k] = w[k];

    // ---- coalesced float4 copy-out of [G, G+nout)
    int nout = OUTEND - G; if (nout > P) nout = P;   // 1088, or 128 on last seg
    float* __restrict__ orow = out + (size_t)row * N_COLS + (G - PAD);
    const float4* __restrict__ s4 = (const float4*)(xs + WF);  // (G-A)==16
    float4* __restrict__ o4 = (float4*)orow;
    const int nv = nout >> 2;
    for (int i = lane; i < nv; i += LANES) o4[i] = s4[i];
}

extern "C" void kernel_launch(void* const* d_in, const int* in_sizes, int n_in,
                              void* d_out, int out_size, void* d_ws, size_t ws_size,
                              hipStream_t stream) {
    const float* x = (const float*)d_in[0];
    const float* b = (const float*)d_in[1];
    const float* a = (const float*)d_in[2];
    float* out = (float*)d_out;
    const int rows = out_size / N_COLS;                // 1024
    const int total_waves = rows * NSEG;               // 31744
    const int blocks = (total_waves + WPB - 1) / WPB;  // 7936
    filtfilt_kernel<<<blocks, TPB, 0, stream>>>(x, b, a, out, rows);
}

// Round 3
// 237.926 us; speedup vs baseline: 1.0067x; 1.0067x over previous
//
#include <hip/hip_runtime.h>

// filtfilt (order-2 biquad, odd-ext pad=9) over 1024 rows x 32768 fp32.
// Barrier-free per-WAVE tiles: intra-wave LDS program order replaces
// __syncthreads (the LDS pipe is in-order per wave).
//
// R6: R5 (stride C=20 -> all-b128 LDS) + explicit phase fences.
// R5's correctness bug: equal strides made per-lane LDS offsets compile-time
// constants, so hipcc could prove per-lane disjointness of {fwd y1-writes @
// 20l+16..32} vs {bwd reads @ 20l+36..52} and hoist the bwd ds_read burst
// above the fwd ds_write burst -- breaking the CROSS-lane RAW (lane l reads
// lane l+1's y1). Per-lane alias analysis cannot see cross-lane hazards.
// Fix: asm-volatile memory clobber + sched_barrier(0) at each phase seam
// (zero runtime cost; hardware DS pipe is in-order per wave, only compile-
// time order was missing). Intra-phase safety is by dataflow: every y1 value
// written depends (via the recurrence) on every earlier x-read, and every
// final output depends on every r-read, so those cannot be reordered.
// Warmup 16/16 (err 0.577^16 ~ 1.5e-4); staged zeros keep row edges exact.

#define N_COLS 32768
#define PAD 9
#define LTOT  (N_COLS + 2 * PAD)   // 32786
#define OUTEND (N_COLS + PAD)      // 32777
#define WF 16
#define WB 16
#define C  20                      // chunk/lane, fwd and bwd (16B-aligned)
#define LANES 64
#define P   (C * LANES)            // 1280 outputs per wave
#define NSEG 26                    // ceil(32768 / 1280)
#define SLOT (WF + P + WB)         // 1312 floats = 5248 B per wave
#define WPB 2
#define TPB 128

// Compile-time ordering fence between LDS phases (no runtime instructions).
#define LDS_PHASE_FENCE() do { asm volatile("" ::: "memory"); \
                               __builtin_amdgcn_sched_barrier(0); } while (0)

__launch_bounds__(TPB, 4)
__global__ void filtfilt_kernel(const float* __restrict__ x,
                                const float* __restrict__ bco,
                                const float* __restrict__ aco,
                                float* __restrict__ out,
                                int rows) {
    __shared__ float xs_all[WPB][SLOT];   // 10,496 B -> 15 blocks/CU
    const int tid = threadIdx.x;
    const int wid = tid >> 6;
    const int lane = tid & 63;
    float* __restrict__ xs = xs_all[wid];

    const int W = blockIdx.x * WPB + wid;  // global wave index
    const int row = W / NSEG;
    const int seg = W - row * NSEG;
    if (row >= rows) return;               // wave-uniform exit, no barriers used

    const float inv_a0 = 1.0f / aco[0];
    const float B0 = bco[0] * inv_a0;
    const float B1 = bco[1] * inv_a0;
    const float B2 = bco[2] * inv_a0;
    const float A1 = aco[1] * inv_a0;
    const float A2 = aco[2] * inv_a0;

    const int G = PAD + seg * P;           // first output position (xe coords)
    const int A = G - WF;                  // slice origin; -7 for seg0
    const float* __restrict__ xrow = x + (size_t)row * N_COLS;

    // ---- stage x via float4 (offsets/counts all %4==0 by design)
    {
        const int g0 = (A - PAD > 0) ? (A - PAD) : 0;
        int g1 = A + SLOT; if (g1 > OUTEND) g1 = OUTEND; g1 -= PAD;
        const int off0 = g0 + PAD - A;     // 0 generic; 16 for seg0
        const float4* __restrict__ xg4 = (const float4*)(xrow + g0);
        float4* __restrict__ s4 = (float4*)(xs + off0);
        const int nvec = (g1 - g0) >> 2;
        for (int i = lane; i < nvec; i += LANES) s4[i] = xg4[i];
    }
    // ---- left edge (seg0): offsets [0,16) = t in [-7, 9): zeros then odd-ext
    if (seg == 0) {
        if (lane < WF) {
            const int t = lane - (WF - PAD);   // -7..8
            xs[lane] = (t >= 0) ? (2.0f * xrow[0] - xrow[PAD - t]) : 0.0f;
        }
    }
    // ---- right edge (last seg): odd-ext then zeros
    if (seg == NSEG - 1) {
        const float x_last = xrow[N_COLS - 1];
        for (int o = (OUTEND - A) + lane; o < SLOT; o += LANES) {
            const int t = A + o;
            xs[o] = (t < LTOT) ? (2.0f * x_last - xrow[2 * N_COLS + PAD - 2 - t])
                               : 0.0f;
        }
    }

    LDS_PHASE_FENCE();   // stage/edge writes  -> fwd reads (cross-lane RAW)

    // ---- forward: 9x b128 read of 36-float window, recurrence in regs,
    // write first 16 y1 (cross region for lane l-1's bwd warmup) as 4x b128.
    // Cross-lane WAR (lane l's y1-write vs lane l+1's x-read of same addr)
    // is ordered by dataflow: each written y1 depends on all earlier x-reads.
    const int f_off = C * lane;            // 16B-aligned, bank-uniform stride
    float v[WF + C] __attribute__((aligned(16)));
#pragma unroll
    for (int k = 0; k < (WF + C) / 4; ++k)
        *(float4*)(v + 4 * k) = *(const float4*)(xs + f_off + 4 * k);
    float fz0 = 0.0f, fz1 = 0.0f;
#pragma unroll
    for (int k = 0; k < WF + C; ++k) {
        const float xv = v[k];
        const float y = fmaf(B0, xv, fz0);
        fz0 = fmaf(-A1, y, fmaf(B1, xv, fz1));
        fz1 = fmaf(B2, xv, -A2 * y);
        v[k] = y;
    }
#pragma unroll
    for (int k = 0; k < WB / 4; ++k)
        *(float4*)(xs + f_off + WF + 4 * k) = *(const float4*)(v + WF + 4 * k);

    // ---- lane-63 extension: 16 more fwd steps (state carried, no warmup)
    // produce y1 [P, P+WB) needed by lane 63's bwd warmup.
    if (lane == LANES - 1) {
        float e[WB] __attribute__((aligned(16)));
#pragma unroll
        for (int k = 0; k < WB / 4; ++k)
            *(float4*)(e + 4 * k) = *(const float4*)(xs + WF + P + 4 * k);
#pragma unroll
        for (int k = 0; k < WB; ++k) {
            const float xv = e[k];
            const float y = fmaf(B0, xv, fz0);
            fz0 = fmaf(-A1, y, fmaf(B1, xv, fz1));
            fz1 = fmaf(B2, xv, -A2 * y);
            e[k] = y;
        }
#pragma unroll
        for (int k = 0; k < WB / 4; ++k)
            *(float4*)(xs + WF + P + 4 * k) = *(const float4*)(e + 4 * k);
    }

    // ---- last seg: zero y1 at positions >= LTOT so bwd zero-state is exact
    if (seg == NSEG - 1) {
        for (int o = (LTOT - A) + lane; o < SLOT; o += LANES) xs[o] = 0.0f;
    }

    LDS_PHASE_FENCE();   // y1 writes (+ext, +zero) -> bwd reads  [THE R5 bug]

    // ---- backward: own y1 (v[16..35], registers) + 4x b128 cross region
    // (lane l+1's first 16 y1, or lane-63 extension).
    const int b0 = C * lane;               // first output position rel G
    float r[WB] __attribute__((aligned(16)));
#pragma unroll
    for (int k = 0; k < WB / 4; ++k)
        *(float4*)(r + 4 * k) = *(const float4*)(xs + b0 + WF + C + 4 * k);
    // last seg: register-held y1 at positions >= LTOT must also read as zero
    if (seg == NSEG - 1) {
        const int LIM = LTOT - G;          // 777
#pragma unroll
        for (int k = 0; k < C; ++k) if (b0 + k >= LIM) v[WF + k] = 0.0f;
    }
    float bz0 = 0.0f, bz1 = 0.0f;
#pragma unroll
    for (int k = C + WB - 1; k >= 0; --k) {
        const float xv = (k < C) ? v[WF + k] : r[k - C];
        const float y = fmaf(B0, xv, bz0);
        bz0 = fmaf(-A1, y, fmaf(B1, xv, bz1));
        bz1 = fmaf(B2, xv, -A2 * y);
        if (k < C) v[WF + k] = y;
    }
    // final outputs in place (each write depends on all r-reads -> ordered
    // vs the cross-lane WAR on the r region)
#pragma unroll
    for (int k = 0; k < C / 4; ++k)
        *(float4*)(xs + b0 + WF + 4 * k) = *(const float4*)(v + WF + 4 * k);

    LDS_PHASE_FENCE();   // final writes -> copy-out reads (cross-lane RAW)

    // ---- coalesced float4 copy-out of [G, G+nout)
    int nout = OUTEND - G; if (nout > P) nout = P;   // 1280, or 768 on last seg
    float* __restrict__ orow = out + (size_t)row * N_COLS + (G - PAD);
    const float4* __restrict__ s4o = (const float4*)(xs + WF);
    float4* __restrict__ o4 = (float4*)orow;
    const int nv = nout >> 2;
    for (int i = lane; i < nv; i += LANES) o4[i] = s4o[i];
}

extern "C" void kernel_launch(void* const* d_in, const int* in_sizes, int n_in,
                              void* d_out, int out_size, void* d_ws, size_t ws_size,
                              hipStream_t stream) {
    const float* x = (const float*)d_in[0];
    const float* b = (const float*)d_in[1];
    const float* a = (const float*)d_in[2];
    float* out = (float*)d_out;
    const int rows = out_size / N_COLS;                // 1024
    const int total_waves = rows * NSEG;               // 26624
    const int blocks = (total_waves + WPB - 1) / WPB;  // 13312
    filtfilt_kernel<<<blocks, TPB, 0, stream>>>(x, b, a, out, rows);
}